// Round 5
// baseline (461.043 us; speedup 1.0000x reference)
//
#include <hip/hip_runtime.h>
#include <cstdint>

// ---------------------------------------------------------------------------
// R-FCN head on MI355X.  Round 5:
//  - FUSE ubuild + poolgemm into k_poolfused: per (64-roi tile, ij) block,
//    A-tile (u vectors) built in-register by direct bin sums over X (fp32,
//    contiguous 64B/thread segments), ds_write into padded LDS (stride 72);
//    B (swizzled Wc) double-buffered via global_load_lds. Kills the 128MB U
//    write + 128MB U read and two dispatch boundaries.
//  - Merge cvt_w1 + cvt_wcomb + desc into one k_prep dispatch.
//  - 6 dispatches total: prep, tpose, conv1, poolfused, reduce, final.
//  Conv1 unchanged (91us, ~755TF, near m97-structure plateau).
// ---------------------------------------------------------------------------

typedef __attribute__((ext_vector_type(8))) short short8;   // 8 bf16 (4 VGPRs)
typedef __attribute__((ext_vector_type(4))) short short4v;
typedef __attribute__((ext_vector_type(4))) float f32x4;

// workspace layout (bytes)
#define OFF_FEATT 0ull          // bf16 [4][4096][2048] = 67108864 ; later P
#define OFF_P     0ull          // bf16 [49][1280][112] = 14049280 (featT dead after conv1)
#define OFF_W1    67108864ull   // bf16 [1024][2048]    = 4194304  (dead after conv1)
#define OFF_WC    71303168ull   // bf16 [128][49][1024] = 12845056 (rows 105..127 zero)
#define OFF_DESC  84148224ull   // int  [1280][49][8]   = 2007040
#define OFF_SCORE 86155264ull   // f32  [1280][128]     = 655360
#define OFF_X     86810624ull   // f32  [4][64][64][1024] = 67108864 -> ends 153919488

__device__ __forceinline__ unsigned short f2bf(float f) {
  unsigned u = __float_as_uint(f);
  u += 0x7fffu + ((u >> 16) & 1u);        // round-to-nearest-even
  return (unsigned short)(u >> 16);
}
__device__ __forceinline__ float bf2f(unsigned short h) {
  return __uint_as_float(((unsigned)h) << 16);
}

// swizzle low-6-bits of a k index: 16B group g (bits 3..5) -> g ^ key
__device__ __forceinline__ int swz6(int k6, int key) {
  return ((((k6 >> 3) & 7) ^ key) << 3) | (k6 & 7);
}

__device__ __forceinline__ void gload16(const void* g, void* l) {
  __builtin_amdgcn_global_load_lds((const __attribute__((address_space(1))) void*)g,
                                   (__attribute__((address_space(3))) void*)l, 16, 0, 0);
}

// --- prep: w1 convert (blocks 0..2047), Wc build (2048..8319), desc (8320..8564)
__global__ __launch_bounds__(256) void k_prep(const float* __restrict__ w1,
                                              const float* __restrict__ wcls,
                                              const float* __restrict__ wbbox,
                                              const float* __restrict__ rois,
                                              unsigned short* __restrict__ w1b,
                                              unsigned short* __restrict__ Wc,
                                              int* __restrict__ desc) {
  int bid = blockIdx.x;
  if (bid < 2048) {
    long e = ((long)bid * 256 + threadIdx.x) * 4;
    int o = (int)(e >> 11), k = (int)(e & 2047);
    float4 q = *(const float4*)(w1 + e);
    short4v s = {(short)f2bf(q.x), (short)f2bf(q.y), (short)f2bf(q.z), (short)f2bf(q.w)};
    int kp = (k & ~63) | swz6(k & 63, o & 7);
    *(short4v*)(w1b + (size_t)o * 2048 + kp) = s;
    return;
  }
  if (bid < 8320) {
    size_t e = ((size_t)(bid - 2048) * 256 + threadIdx.x) * 4;
    int c = (int)(e / 50176);
    int rem = (int)(e - (size_t)c * 50176);
    int ij = rem >> 10, k = rem & 1023;
    float4 q = make_float4(0.f, 0.f, 0.f, 0.f);
    if (c < 21)       q = *(const float4*)(wcls + (size_t)(c * 49 + ij) * 1024 + k);
    else if (c < 105) q = *(const float4*)(wbbox + (size_t)((c - 21) * 49 + ij) * 1024 + k);
    short4v s = {(short)f2bf(q.x), (short)f2bf(q.y), (short)f2bf(q.z), (short)f2bf(q.w)};
    int kp = (k & ~63) | swz6(k & 63, c & 7);
    *(short4v*)(Wc + ((size_t)(c * 49 + ij) * 1024 + kp)) = s;
    return;
  }
  int t = (bid - 8320) * 256 + threadIdx.x;
  if (t >= 1280 * 49) return;
  int roi = t / 49, ij = t - roi * 49;
  int* d = desc + (size_t)t * 8;
  if (roi >= 1200) { d[0] = 0; d[1] = 0; d[2] = 0; d[3] = 0; d[4] = 0; ((float*)d)[5] = 0.f; return; }
  const float* r = rois + (size_t)roi * 5;
  int b = (int)r[0];
  // fp32 ops mirror the reference exactly (unfused mul/add, floor/ceil, clip)
  float x1 = __fmul_rn(floorf(__fadd_rn(r[1], 0.5f)), 0.0625f);
  float y1 = __fmul_rn(floorf(__fadd_rn(r[2], 0.5f)), 0.0625f);
  float x2 = __fmul_rn(floorf(__fadd_rn(__fadd_rn(r[3], 1.0f), 0.5f)), 0.0625f);
  float y2 = __fmul_rn(floorf(__fadd_rn(__fadd_rn(r[4], 1.0f), 0.5f)), 0.0625f);
  float bw = __fdiv_rn(fmaxf(__fsub_rn(x2, x1), 0.1f), 7.0f);
  float bh = __fdiv_rn(fmaxf(__fsub_rn(y2, y1), 0.1f), 7.0f);
  int i = ij / 7, j = ij - (ij / 7) * 7;
  float fi = (float)i, fj = (float)j;
  int hs = (int)fminf(fmaxf(floorf(__fadd_rn(__fmul_rn(fi, bh), y1)), 0.f), 64.f);
  int he = (int)fminf(fmaxf(ceilf(__fadd_rn(__fmul_rn(__fadd_rn(fi, 1.f), bh), y1)), 0.f), 64.f);
  int wsx = (int)fminf(fmaxf(floorf(__fadd_rn(__fmul_rn(fj, bw), x1)), 0.f), 64.f);
  int we = (int)fminf(fmaxf(ceilf(__fadd_rn(__fmul_rn(__fadd_rn(fj, 1.f), bw), x1)), 0.f), 64.f);
  int dh = max(he - hs, 0), dw = max(we - wsx, 0);
  float inv = (dh * dw > 0) ? 1.0f / (float)(dh * dw) : 0.f;
  d[0] = b; d[1] = hs; d[2] = he; d[3] = wsx; d[4] = we;
  ((float*)d)[5] = inv;
}

// --- base_feat [b][c][s] fp32 -> featT [b][s][c] bf16 (swizzled) -----------
__global__ __launch_bounds__(256) void k_tpose(const float* __restrict__ src,
                                               unsigned short* __restrict__ dst) {
  __shared__ float tile[64][65];
  int s0 = blockIdx.x * 64, c0 = blockIdx.y * 64, b = blockIdx.z;
  int tx = threadIdx.x & 63, ty = threadIdx.x >> 6;
  const float* sp = src + ((size_t)b * 2048 + c0) * 4096 + s0;
#pragma unroll
  for (int i = 0; i < 16; i++) {
    int cl = ty * 16 + i;
    tile[cl][tx] = sp[(size_t)cl * 4096 + tx];
  }
  __syncthreads();
  unsigned short* dp = dst + ((size_t)b * 4096 + s0) * 2048 + c0;
  int c4 = (threadIdx.x & 15) * 4;      // channel start (within 64-chunk)
  int sy = threadIdx.x >> 4;            // spatial row
#pragma unroll
  for (int i = 0; i < 4; i++) {
    int sl = i * 16 + sy;
    int key = sl & 7;
    short4v v = {(short)f2bf(tile[c4 + 0][sl]), (short)f2bf(tile[c4 + 1][sl]),
                 (short)f2bf(tile[c4 + 2][sl]), (short)f2bf(tile[c4 + 3][sl])};
    *(short4v*)(dp + (size_t)sl * 2048 + swz6(c4, key)) = v;  // 8B store, same group
  }
}

// --- conv1: X[b][s][o] = relu(sum_k featT[b][s][k] * w1[o][k]) -------------
__global__ __launch_bounds__(256) void k_gemm_conv1(const short* __restrict__ A,
                                                    const short* __restrict__ Bw,
                                                    float* __restrict__ X) {
  int mt = blockIdx.x, nt = blockIdx.y, b = blockIdx.z;
  __shared__ short As[128 * 64];   // [m][k] rows k-contiguous (swizzled image)
  __shared__ short Bs[128 * 64];   // [n][k]
  int tid = threadIdx.x, lane = tid & 63, wave = tid >> 6;
  int wm = wave >> 1, wn = wave & 1;
  f32x4 acc[4][4];
#pragma unroll
  for (int i = 0; i < 4; i++)
#pragma unroll
    for (int j = 0; j < 4; j++) acc[i][j] = (f32x4){0.f, 0.f, 0.f, 0.f};

  const short* Ab = A + ((size_t)b * 4096 + (size_t)mt * 128) * 2048;
  const short* Bb = Bw + (size_t)nt * 128 * 2048;
  int lr = lane >> 3;          // row within 8-row chunk
  int lc = (lane & 7) * 8;     // k element
  int key = lane & 7;

  for (int k0 = 0; k0 < 2048; k0 += 64) {
#pragma unroll
    for (int i = 0; i < 4; i++) {
      int row = i * 32 + wave * 8 + lr;
      gload16(Ab + (size_t)row * 2048 + k0 + lc, (char*)As + (i * 32 + wave * 8) * 128);
      gload16(Bb + (size_t)row * 2048 + k0 + lc, (char*)Bs + (i * 32 + wave * 8) * 128);
    }
    __syncthreads();
#pragma unroll
    for (int kt = 0; kt < 2; kt++) {
      int ko = (((kt << 2) | (lane >> 4)) ^ key) << 3;   // swizzled fragment offset
      short8 af[4], bfr[4];
#pragma unroll
      for (int i = 0; i < 4; i++)
        af[i] = *(const short8*)(As + (wm * 64 + i * 16 + (lane & 15)) * 64 + ko);
#pragma unroll
      for (int j = 0; j < 4; j++)
        bfr[j] = *(const short8*)(Bs + (wn * 64 + j * 16 + (lane & 15)) * 64 + ko);
#pragma unroll
      for (int i = 0; i < 4; i++)
#pragma unroll
        for (int j = 0; j < 4; j++)
          acc[i][j] = __builtin_amdgcn_mfma_f32_16x16x32_bf16(af[i], bfr[j], acc[i][j], 0, 0, 0);
    }
    __syncthreads();
  }
  float* Xb = X + ((size_t)b * 4096 + (size_t)mt * 128) * 1024 + nt * 128;
#pragma unroll
  for (int i = 0; i < 4; i++)
#pragma unroll
    for (int j = 0; j < 4; j++) {
      int row = wm * 64 + i * 16 + (lane >> 4) * 4;
      int col = wn * 64 + j * 16 + (lane & 15);
#pragma unroll
      for (int r = 0; r < 4; r++)
        Xb[(size_t)(row + r) * 1024 + col] = fmaxf(acc[i][j][r], 0.f);
    }
}

// --- fused pool+GEMM: P[ij][roi][c] = sum_k u[roi][ij][k] * Wc[c][ij][k] ---
// Block (mt in [0,20), ij in [0,49)). A-tile built in-register from X by
// direct bin sums (contiguous 64B/thread), ds_write to padded LDS; B tile
// double-buffered via global_load_lds on swizzled Wc.
__global__ __launch_bounds__(256, 3) void k_poolfused(const float* __restrict__ X,
                                                      const int* __restrict__ desc,
                                                      const unsigned short* __restrict__ Wc,
                                                      unsigned short* __restrict__ P) {
  int mt = blockIdx.x;   // 0..19 (64-roi tile)
  int ij = blockIdx.y;   // 0..48
  __shared__ short As[2][64 * 72];   // [roi][k], pad 72 (144B rows, 16B-aligned)
  __shared__ short Bs[2][128 * 64];  // [c][k] swizzled image
  int tid = threadIdx.x, lane = tid & 63, wave = tid >> 6;
  int r = tid >> 2, q = tid & 3;     // gather role: roi row, k-quarter (16 floats)

  const int* d = desc + ((size_t)(mt * 64 + r) * 49 + ij) * 8;
  int b = d[0], hs = d[1], he = d[2], wsx = d[3], we = d[4];
  float inv = ((const float*)d)[5];
  const float* Xq = X + (size_t)q * 16;  // quarter offset folded in

  // B staging base (global addr incl. lane pattern; gload16 adds lane*16B on LDS side)
  const unsigned short* Bb = Wc + (size_t)ij * 1024 +
                             (size_t)(wave * 8 + (lane >> 3)) * 49 * 1024 + (lane & 7) * 8;
  int key = lane & 7;

  f32x4 acc[4][2];
#pragma unroll
  for (int i = 0; i < 4; i++)
#pragma unroll
    for (int j = 0; j < 2; j++) acc[i][j] = (f32x4){0.f, 0.f, 0.f, 0.f};

  float s[16];

  // gather chunk k0 -> s[16] (fp32 bin sum over cells, identical order to ubuild)
  auto gather = [&](int k0) {
#pragma unroll
    for (int z = 0; z < 16; z++) s[z] = 0.f;
    for (int h = hs; h < he; h++) {
      const float* rp = Xq + ((size_t)((b * 64 + h) * 64 + wsx)) * 1024 + k0;
      for (int w = wsx; w < we; w++) {
        float4 a0 = *(const float4*)(rp + 0);
        float4 a1 = *(const float4*)(rp + 4);
        float4 a2 = *(const float4*)(rp + 8);
        float4 a3 = *(const float4*)(rp + 12);
        s[0] += a0.x; s[1] += a0.y; s[2] += a0.z; s[3] += a0.w;
        s[4] += a1.x; s[5] += a1.y; s[6] += a1.z; s[7] += a1.w;
        s[8] += a2.x; s[9] += a2.y; s[10] += a2.z; s[11] += a2.w;
        s[12] += a3.x; s[13] += a3.y; s[14] += a3.z; s[15] += a3.w;
        rp += 1024;
      }
    }
  };
  auto writeA = [&](int buf) {
    short8 v0 = {(short)f2bf(s[0] * inv), (short)f2bf(s[1] * inv),
                 (short)f2bf(s[2] * inv), (short)f2bf(s[3] * inv),
                 (short)f2bf(s[4] * inv), (short)f2bf(s[5] * inv),
                 (short)f2bf(s[6] * inv), (short)f2bf(s[7] * inv)};
    short8 v1 = {(short)f2bf(s[8] * inv), (short)f2bf(s[9] * inv),
                 (short)f2bf(s[10] * inv), (short)f2bf(s[11] * inv),
                 (short)f2bf(s[12] * inv), (short)f2bf(s[13] * inv),
                 (short)f2bf(s[14] * inv), (short)f2bf(s[15] * inv)};
    *(short8*)&As[buf][r * 72 + q * 16] = v0;
    *(short8*)&As[buf][r * 72 + q * 16 + 8] = v1;
  };
  auto loadB = [&](int k0, int buf) {
#pragma unroll
    for (int i = 0; i < 4; i++)
      gload16(Bb + (size_t)(i * 32) * 49 * 1024 + k0,
              (char*)Bs[buf] + (i * 32 + wave * 8) * 128);
  };

  // prologue: chunk 0
  gather(0);
  loadB(0, 0);
  __syncthreads();           // Bs[0] ready (vmcnt drain), everyone's s[] ready
  writeA(0);

  for (int kc = 0; kc < 16; kc++) {
    int cur = kc & 1;
    if (kc < 15) {
      loadB((kc + 1) * 64, cur ^ 1);
      gather((kc + 1) * 64);
    }
    __syncthreads();         // As[cur] visible; Bs[cur] drained (prev iter's barrier)
#pragma unroll
    for (int kt = 0; kt < 2; kt++) {
      int ko = kt * 32 + (lane >> 4) * 8;                          // A: no swizzle
      int kob = (((kt << 2) | (lane >> 4)) ^ key) << 3;            // B: swizzled
      short8 af[4], bfr[2];
#pragma unroll
      for (int i = 0; i < 4; i++)
        af[i] = *(const short8*)(&As[cur][(i * 16 + (lane & 15)) * 72 + ko]);
#pragma unroll
      for (int j = 0; j < 2; j++)
        bfr[j] = *(const short8*)(&Bs[cur][(wave * 32 + j * 16 + (lane & 15)) * 64 + kob]);
#pragma unroll
      for (int i = 0; i < 4; i++)
#pragma unroll
        for (int j = 0; j < 2; j++)
          acc[i][j] = __builtin_amdgcn_mfma_f32_16x16x32_bf16(af[i], bfr[j], acc[i][j], 0, 0, 0);
    }
    if (kc < 15) writeA(cur ^ 1);   // safe: all waves passed this iter's barrier
  }

  // store partials P[ij][1280][112] bf16 (c>=112 dropped; only c<105 used)
  unsigned short* Pb = P + (size_t)ij * 1280 * 112;
#pragma unroll
  for (int i = 0; i < 4; i++)
#pragma unroll
    for (int j = 0; j < 2; j++) {
      int cc = wave * 32 + j * 16 + (lane & 15);
      if (cc < 112) {
        int rbase = mt * 64 + i * 16 + (lane >> 4) * 4;
#pragma unroll
        for (int r2 = 0; r2 < 4; r2++)
          Pb[(size_t)(rbase + r2) * 112 + cc] = f2bf(acc[i][j][r2]);
      }
    }
}

// --- reduce 49 ij-partials -> score ----------------------------------------
__global__ __launch_bounds__(256) void k_reduce(const unsigned short* __restrict__ P,
                                                float* __restrict__ score) {
  int t = blockIdx.x * 256 + threadIdx.x;   // 1280*112
  if (t >= 1280 * 112) return;
  int roi = t / 112, c = t - roi * 112;
  float s = 0.f;
#pragma unroll 7
  for (int ij = 0; ij < 49; ij++) s += bf2f(P[(size_t)ij * 1280 * 112 + t]);
  score[(size_t)roi * 128 + c] = s;
}

// --- epilogue: softmax(cls/49) + bbox/49 -----------------------------------
__global__ __launch_bounds__(256) void k_final(const float* __restrict__ score,
                                               float* __restrict__ out) {
  int t = blockIdx.x * 256 + threadIdx.x;
  if (t < 1200) {
    float s[21];
    float mx = -1e30f;
#pragma unroll
    for (int c = 0; c < 21; c++) {
      s[c] = score[(size_t)t * 128 + c] * (1.f / 49.f);
      mx = fmaxf(mx, s[c]);
    }
    float sum = 0.f;
#pragma unroll
    for (int c = 0; c < 21; c++) { s[c] = expf(s[c] - mx); sum += s[c]; }
    float rs = 1.f / sum;
#pragma unroll
    for (int c = 0; c < 21; c++) out[(size_t)t * 21 + c] = s[c] * rs;
  }
  if (t < 100800) {
    int roi = t / 84, c = t - (t / 84) * 84;
    out[25200 + t] = score[(size_t)roi * 128 + 21 + c] * (1.f / 49.f);
  }
}

extern "C" void kernel_launch(void* const* d_in, const int* in_sizes, int n_in,
                              void* d_out, int out_size, void* d_ws, size_t ws_size,
                              hipStream_t stream) {
  const float* base_feat = (const float*)d_in[0];
  const float* rois      = (const float*)d_in[1];
  const float* w_conv1   = (const float*)d_in[2];
  const float* w_cls     = (const float*)d_in[3];
  const float* w_bbox    = (const float*)d_in[4];
  float* out = (float*)d_out;
  char* ws = (char*)d_ws;

  unsigned short* featT = (unsigned short*)(ws + OFF_FEATT);
  unsigned short* w1b   = (unsigned short*)(ws + OFF_W1);
  unsigned short* Wc    = (unsigned short*)(ws + OFF_WC);
  int*            desc  = (int*)(ws + OFF_DESC);
  float*          score = (float*)(ws + OFF_SCORE);
  float*          X     = (float*)(ws + OFF_X);
  unsigned short* P     = (unsigned short*)(ws + OFF_P);   // aliases featT (dead)

  k_prep<<<8565, 256, 0, stream>>>(w_conv1, w_cls, w_bbox, rois, w1b, Wc, desc);
  k_tpose<<<dim3(64, 32, 4), 256, 0, stream>>>(base_feat, featT);
  k_gemm_conv1<<<dim3(32, 8, 4), 256, 0, stream>>>((const short*)featT, (const short*)w1b, X);
  k_poolfused<<<dim3(20, 49), 256, 0, stream>>>(X, desc, Wc, P);
  k_reduce<<<560, 256, 0, stream>>>(P, score);
  k_final<<<394, 256, 0, stream>>>(score, out);
}

// Round 6
// 440.623 us; speedup vs baseline: 1.0463x; 1.0463x over previous
//
#include <hip/hip_runtime.h>
#include <cstdint>

// ---------------------------------------------------------------------------
// R-FCN head on MI355X.  Round 6:
//  - Per-roi ubuild (1280 independent blocks, no barriers): column-sum sharing
//    over the roi footprint cuts logical X reads ~2.3x; scalar-uniform branch
//    per bin-col. U relaid out as [ij][roi][k] (contiguous slabs).
//  - Wc relaid out as [ij][c][k]; poolgemm3 = conv1 clone (128x128 tile,
//    grid (nroi/128, 49)) streaming two dense 256KB slabs per block.
//  - tpose vectorized: float4 global reads (16B/lane), LDS transpose, short8
//    swizzled stores.
//  - reduce+final merged into k_finalize (P -> softmax/scale -> out).
//  XOR-swizzled LDS-image layouts retained everywhere (conflicts = 0).
// ---------------------------------------------------------------------------

typedef __attribute__((ext_vector_type(8))) short short8;   // 8 bf16 (4 VGPRs)
typedef __attribute__((ext_vector_type(4))) short short4v;
typedef __attribute__((ext_vector_type(4))) float f32x4;

// workspace layout (bytes)
#define OFF_FEATT 0ull          // bf16 [4][4096][2048] = 67108864 ; dead after conv1
#define OFF_U2    0ull          // bf16 [49][640][1024] = 64225280   (2-half path)
#define OFF_P2    64225280ull   // bf16 [49][640][112]  = 7024640  -> 71249920
#define OFF_W1    67108864ull   // bf16 [1024][2048]    = 4194304  (dead after conv1)
#define OFF_WC    71303168ull   // bf16 [49][128][1024] = 12845056 (c rows 105..127 zero)
#define OFF_DESC  84148224ull   // int  [1280][49][8]   = 2007040
#define OFF_SCORE 86155264ull   // f32  [1280][128]     = 655360 (unused, kept for layout)
#define OFF_X     86810624ull   // f32  [4][64][64][1024] = 67108864 -> ends 153919488
#define OFF_U1    153919488ull  // bf16 [49][1280][1024] = 128450560 (1-pass)
#define OFF_P1    282370048ull  // bf16 [49][1280][112]  = 14049280 -> ends 296419328
#define ONEPASS_BYTES 296419328ull

__device__ __forceinline__ unsigned short f2bf(float f) {
  unsigned u = __float_as_uint(f);
  u += 0x7fffu + ((u >> 16) & 1u);        // round-to-nearest-even
  return (unsigned short)(u >> 16);
}
__device__ __forceinline__ float bf2f(unsigned short h) {
  return __uint_as_float(((unsigned)h) << 16);
}

// swizzle low-6-bits of a k index: 16B group g (bits 3..5) -> g ^ key
__device__ __forceinline__ int swz6(int k6, int key) {
  return ((((k6 >> 3) & 7) ^ key) << 3) | (k6 & 7);
}

__device__ __forceinline__ void gload16(const void* g, void* l) {
  __builtin_amdgcn_global_load_lds((const __attribute__((address_space(1))) void*)g,
                                   (__attribute__((address_space(3))) void*)l, 16, 0, 0);
}

// --- prep: w1 convert (blocks 0..2047), Wc build (2048..8319), desc (8320..8564)
__global__ __launch_bounds__(256) void k_prep(const float* __restrict__ w1,
                                              const float* __restrict__ wcls,
                                              const float* __restrict__ wbbox,
                                              const float* __restrict__ rois,
                                              unsigned short* __restrict__ w1b,
                                              unsigned short* __restrict__ Wc,
                                              int* __restrict__ desc) {
  int bid = blockIdx.x;
  if (bid < 2048) {
    long e = ((long)bid * 256 + threadIdx.x) * 4;
    int o = (int)(e >> 11), k = (int)(e & 2047);
    float4 q = *(const float4*)(w1 + e);
    short4v s = {(short)f2bf(q.x), (short)f2bf(q.y), (short)f2bf(q.z), (short)f2bf(q.w)};
    int kp = (k & ~63) | swz6(k & 63, o & 7);
    *(short4v*)(w1b + (size_t)o * 2048 + kp) = s;
    return;
  }
  if (bid < 8320) {
    size_t e = ((size_t)(bid - 2048) * 256 + threadIdx.x) * 4;
    int c = (int)(e / 50176);
    int rem = (int)(e - (size_t)c * 50176);
    int ij = rem >> 10, k = rem & 1023;
    float4 q = make_float4(0.f, 0.f, 0.f, 0.f);
    if (c < 21)       q = *(const float4*)(wcls + (size_t)(c * 49 + ij) * 1024 + k);
    else if (c < 105) q = *(const float4*)(wbbox + (size_t)((c - 21) * 49 + ij) * 1024 + k);
    short4v s = {(short)f2bf(q.x), (short)f2bf(q.y), (short)f2bf(q.z), (short)f2bf(q.w)};
    int kp = (k & ~63) | swz6(k & 63, c & 7);
    *(short4v*)(Wc + ((size_t)(ij * 128 + c) * 1024 + kp)) = s;   // [ij][c][k]
    return;
  }
  int t = (bid - 8320) * 256 + threadIdx.x;
  if (t >= 1280 * 49) return;
  int roi = t / 49, ij = t - roi * 49;
  int* d = desc + (size_t)t * 8;
  if (roi >= 1200) { d[0] = 0; d[1] = 0; d[2] = 0; d[3] = 0; d[4] = 0; ((float*)d)[5] = 0.f; return; }
  const float* r = rois + (size_t)roi * 5;
  int b = (int)r[0];
  // fp32 ops mirror the reference exactly (unfused mul/add, floor/ceil, clip)
  float x1 = __fmul_rn(floorf(__fadd_rn(r[1], 0.5f)), 0.0625f);
  float y1 = __fmul_rn(floorf(__fadd_rn(r[2], 0.5f)), 0.0625f);
  float x2 = __fmul_rn(floorf(__fadd_rn(__fadd_rn(r[3], 1.0f), 0.5f)), 0.0625f);
  float y2 = __fmul_rn(floorf(__fadd_rn(__fadd_rn(r[4], 1.0f), 0.5f)), 0.0625f);
  float bw = __fdiv_rn(fmaxf(__fsub_rn(x2, x1), 0.1f), 7.0f);
  float bh = __fdiv_rn(fmaxf(__fsub_rn(y2, y1), 0.1f), 7.0f);
  int i = ij / 7, j = ij - (ij / 7) * 7;
  float fi = (float)i, fj = (float)j;
  int hs = (int)fminf(fmaxf(floorf(__fadd_rn(__fmul_rn(fi, bh), y1)), 0.f), 64.f);
  int he = (int)fminf(fmaxf(ceilf(__fadd_rn(__fmul_rn(__fadd_rn(fi, 1.f), bh), y1)), 0.f), 64.f);
  int wsx = (int)fminf(fmaxf(floorf(__fadd_rn(__fmul_rn(fj, bw), x1)), 0.f), 64.f);
  int we = (int)fminf(fmaxf(ceilf(__fadd_rn(__fmul_rn(__fadd_rn(fj, 1.f), bw), x1)), 0.f), 64.f);
  int dh = max(he - hs, 0), dw = max(we - wsx, 0);
  float inv = (dh * dw > 0) ? 1.0f / (float)(dh * dw) : 0.f;
  d[0] = b; d[1] = hs; d[2] = he; d[3] = wsx; d[4] = we;
  ((float*)d)[5] = inv;
}

// --- base_feat [b][c][s] fp32 -> featT [b][s][c] bf16 (swizzled), float4 IO -
__global__ __launch_bounds__(256) void k_tpose(const float* __restrict__ src,
                                               unsigned short* __restrict__ dst) {
  __shared__ float tile[64][65];
  int s0 = blockIdx.x * 64, c0 = blockIdx.y * 64, b = blockIdx.z;
  int cl = threadIdx.x >> 4;            // 0..15
  int sv = (threadIdx.x & 15) * 4;      // 0..60
  const float* sp = src + ((size_t)(b * 2048 + c0)) * 4096 + s0;
#pragma unroll
  for (int i = 0; i < 4; i++) {
    int c = i * 16 + cl;
    float4 q = *(const float4*)(sp + (size_t)c * 4096 + sv);
    tile[c][sv + 0] = q.x; tile[c][sv + 1] = q.y;
    tile[c][sv + 2] = q.z; tile[c][sv + 3] = q.w;
  }
  __syncthreads();
  int s = threadIdx.x >> 2;             // 0..63
  int cq = (threadIdx.x & 3) * 16;      // 0,16,32,48
  int key = s & 7;
  unsigned short* dp = dst + ((size_t)(b * 4096 + s0 + s)) * 2048 + c0;
  float q[16];
#pragma unroll
  for (int z = 0; z < 16; z++) q[z] = tile[cq + z][s];
  short8 v0 = {(short)f2bf(q[0]), (short)f2bf(q[1]), (short)f2bf(q[2]), (short)f2bf(q[3]),
               (short)f2bf(q[4]), (short)f2bf(q[5]), (short)f2bf(q[6]), (short)f2bf(q[7])};
  short8 v1 = {(short)f2bf(q[8]), (short)f2bf(q[9]), (short)f2bf(q[10]), (short)f2bf(q[11]),
               (short)f2bf(q[12]), (short)f2bf(q[13]), (short)f2bf(q[14]), (short)f2bf(q[15])};
  int ga = cq >> 3;                     // 16B group index (0,2,4,6)
  *(short8*)(dp + (((ga + 0) ^ key) << 3)) = v0;
  *(short8*)(dp + (((ga + 1) ^ key) << 3)) = v1;
}

// --- conv1: X[b][s][o] = relu(sum_k featT[b][s][k] * w1[o][k]) -------------
__global__ __launch_bounds__(256) void k_gemm_conv1(const short* __restrict__ A,
                                                    const short* __restrict__ Bw,
                                                    float* __restrict__ X) {
  int mt = blockIdx.x, nt = blockIdx.y, b = blockIdx.z;
  __shared__ short As[128 * 64];   // [m][k] rows k-contiguous (swizzled image)
  __shared__ short Bs[128 * 64];   // [n][k]
  int tid = threadIdx.x, lane = tid & 63, wave = tid >> 6;
  int wm = wave >> 1, wn = wave & 1;
  f32x4 acc[4][4];
#pragma unroll
  for (int i = 0; i < 4; i++)
#pragma unroll
    for (int j = 0; j < 4; j++) acc[i][j] = (f32x4){0.f, 0.f, 0.f, 0.f};

  const short* Ab = A + ((size_t)b * 4096 + (size_t)mt * 128) * 2048;
  const short* Bb = Bw + (size_t)nt * 128 * 2048;
  int lr = lane >> 3;          // row within 8-row chunk
  int lc = (lane & 7) * 8;     // k element
  int key = lane & 7;

  for (int k0 = 0; k0 < 2048; k0 += 64) {
#pragma unroll
    for (int i = 0; i < 4; i++) {
      int row = i * 32 + wave * 8 + lr;
      gload16(Ab + (size_t)row * 2048 + k0 + lc, (char*)As + (i * 32 + wave * 8) * 128);
      gload16(Bb + (size_t)row * 2048 + k0 + lc, (char*)Bs + (i * 32 + wave * 8) * 128);
    }
    __syncthreads();
#pragma unroll
    for (int kt = 0; kt < 2; kt++) {
      int ko = (((kt << 2) | (lane >> 4)) ^ key) << 3;   // swizzled fragment offset
      short8 af[4], bfr[4];
#pragma unroll
      for (int i = 0; i < 4; i++)
        af[i] = *(const short8*)(As + (wm * 64 + i * 16 + (lane & 15)) * 64 + ko);
#pragma unroll
      for (int j = 0; j < 4; j++)
        bfr[j] = *(const short8*)(Bs + (wn * 64 + j * 16 + (lane & 15)) * 64 + ko);
#pragma unroll
      for (int i = 0; i < 4; i++)
#pragma unroll
        for (int j = 0; j < 4; j++)
          acc[i][j] = __builtin_amdgcn_mfma_f32_16x16x32_bf16(af[i], bfr[j], acc[i][j], 0, 0, 0);
    }
    __syncthreads();
  }
  float* Xb = X + ((size_t)b * 4096 + (size_t)mt * 128) * 1024 + nt * 128;
#pragma unroll
  for (int i = 0; i < 4; i++)
#pragma unroll
    for (int j = 0; j < 4; j++) {
      int row = wm * 64 + i * 16 + (lane >> 4) * 4;
      int col = wn * 64 + j * 16 + (lane & 15);
#pragma unroll
      for (int r = 0; r < 4; r++)
        Xb[(size_t)(row + r) * 1024 + col] = fmaxf(acc[i][j][r], 0.f);
    }
}

// --- u-build, per-roi: one block per roi, no barriers, column-sum sharing --
// Thread owns k-quad; sweeps footprint rows once per bin-row, adding each
// cell into every bin-col containing it (w/ws/we are wave-uniform -> scalar
// branches). Bin accumulation order (h asc, w asc) identical to before.
// U layout: [ij][nroi][k] bf16, swizzled per roi&7.
__global__ __launch_bounds__(256) void k_ubuild(const float* __restrict__ X,
                                                const int* __restrict__ desc,
                                                unsigned short* __restrict__ U,
                                                int nroi) {
  int lroi = blockIdx.x;
  const int* db = desc + (size_t)lroi * 49 * 8;
  int b = db[0];
  int wsj[7], wej[7];
#pragma unroll
  for (int j = 0; j < 7; j++) { wsj[j] = db[j * 8 + 3]; wej[j] = db[j * 8 + 4]; }
  int wlo = wsj[0], whi = wej[6];
  int k = threadIdx.x * 4;
  const float* Xb = X + (size_t)b * 64 * 64 * 1024 + k;
  int kp = (k & ~63) | swz6(k & 63, lroi & 7);
  unsigned short* Ur = U + (size_t)lroi * 1024 + kp;
  for (int i = 0; i < 7; i++) {
    int hs = db[(i * 7) * 8 + 1], he = db[(i * 7) * 8 + 2];
    float ca[7][4];
#pragma unroll
    for (int j = 0; j < 7; j++) { ca[j][0] = 0.f; ca[j][1] = 0.f; ca[j][2] = 0.f; ca[j][3] = 0.f; }
    for (int h = hs; h < he; h++) {
      const float* rp = Xb + ((size_t)(h * 64 + wlo)) * 1024;
      for (int w = wlo; w < whi; w++) {
        float4 q = *(const float4*)rp;
        rp += 1024;
#pragma unroll
        for (int j = 0; j < 7; j++) {
          if (w >= wsj[j] && w < wej[j]) {
            ca[j][0] += q.x; ca[j][1] += q.y; ca[j][2] += q.z; ca[j][3] += q.w;
          }
        }
      }
    }
#pragma unroll
    for (int j = 0; j < 7; j++) {
      float inv = ((const float*)db)[(i * 7 + j) * 8 + 5];
      short4v s = {(short)f2bf(ca[j][0] * inv), (short)f2bf(ca[j][1] * inv),
                   (short)f2bf(ca[j][2] * inv), (short)f2bf(ca[j][3] * inv)};
      *(short4v*)(Ur + (size_t)(i * 7 + j) * nroi * 1024) = s;
    }
  }
}

// --- pool-GEMM (conv1 clone): P[ij][roi][c] = sum_k U[ij][roi][k]*Wc[ij][c][k]
__global__ __launch_bounds__(256) void k_poolgemm3(const unsigned short* __restrict__ U,
                                                   const unsigned short* __restrict__ Wc,
                                                   unsigned short* __restrict__ P,
                                                   int nroi) {
  int mt = blockIdx.x, ij = blockIdx.y;
  __shared__ short As[128 * 64];
  __shared__ short Bs[128 * 64];
  int tid = threadIdx.x, lane = tid & 63, wave = tid >> 6;
  int wm = wave >> 1, wn = wave & 1;
  f32x4 acc[4][4];
#pragma unroll
  for (int i = 0; i < 4; i++)
#pragma unroll
    for (int j = 0; j < 4; j++) acc[i][j] = (f32x4){0.f, 0.f, 0.f, 0.f};

  const unsigned short* Ab = U + ((size_t)ij * nroi + mt * 128) * 1024;
  const unsigned short* Bb = Wc + (size_t)ij * 128 * 1024;
  int lr = lane >> 3, lc = (lane & 7) * 8, key = lane & 7;

  for (int k0 = 0; k0 < 1024; k0 += 64) {
#pragma unroll
    for (int i = 0; i < 4; i++) {
      int row = i * 32 + wave * 8 + lr;
      gload16(Ab + (size_t)row * 1024 + k0 + lc, (char*)As + (i * 32 + wave * 8) * 128);
      gload16(Bb + (size_t)row * 1024 + k0 + lc, (char*)Bs + (i * 32 + wave * 8) * 128);
    }
    __syncthreads();
#pragma unroll
    for (int kt = 0; kt < 2; kt++) {
      int ko = (((kt << 2) | (lane >> 4)) ^ key) << 3;
      short8 af[4], bfr[4];
#pragma unroll
      for (int i = 0; i < 4; i++)
        af[i] = *(const short8*)(As + (wm * 64 + i * 16 + (lane & 15)) * 64 + ko);
#pragma unroll
      for (int j = 0; j < 4; j++)
        bfr[j] = *(const short8*)(Bs + (wn * 64 + j * 16 + (lane & 15)) * 64 + ko);
#pragma unroll
      for (int i = 0; i < 4; i++)
#pragma unroll
        for (int j = 0; j < 4; j++)
          acc[i][j] = __builtin_amdgcn_mfma_f32_16x16x32_bf16(af[i], bfr[j], acc[i][j], 0, 0, 0);
    }
    __syncthreads();
  }
  // store partials P[ij][nroi][112] bf16 (c>=112 dropped; only c<105 used)
  unsigned short* Pb = P + (size_t)ij * nroi * 112;
#pragma unroll
  for (int i = 0; i < 4; i++)
#pragma unroll
    for (int j = 0; j < 4; j++) {
      int col = wn * 64 + j * 16 + (lane & 15);
      if (col < 112) {
        int rbase = mt * 128 + wm * 64 + i * 16 + (lane >> 4) * 4;
#pragma unroll
        for (int r = 0; r < 4; r++)
          Pb[(size_t)(rbase + r) * 112 + col] = f2bf(acc[i][j][r]);
      }
    }
}

// --- finalize: sum 49 ij-partials -> softmax(cls/49) + bbox/49 -> out ------
__global__ __launch_bounds__(256) void k_finalize(const unsigned short* __restrict__ P,
                                                  float* __restrict__ out,
                                                  int nroi, int roiBase) {
  __shared__ float sc[2][112];
  int half = threadIdx.x >> 7, t = threadIdx.x & 127;
  int lroi = blockIdx.x * 2 + half;
  int roi = roiBase + lroi;
  if (t < 112) {
    float s = 0.f;
#pragma unroll 7
    for (int ij = 0; ij < 49; ij++) s += bf2f(P[((size_t)ij * nroi + lroi) * 112 + t]);
    sc[half][t] = s;
  }
  __syncthreads();
  if (roi < 1200) {
    if (t < 21) {
      float mx = -1e30f;
#pragma unroll
      for (int c = 0; c < 21; c++) mx = fmaxf(mx, sc[half][c] * (1.f / 49.f));
      float sum = 0.f;
#pragma unroll
      for (int c = 0; c < 21; c++) sum += expf(sc[half][c] * (1.f / 49.f) - mx);
      float rs = 1.f / sum;
      out[(size_t)roi * 21 + t] = expf(sc[half][t] * (1.f / 49.f) - mx) * rs;
    }
    if (t < 84)
      out[25200 + (size_t)roi * 84 + t] = sc[half][21 + t] * (1.f / 49.f);
  }
}

extern "C" void kernel_launch(void* const* d_in, const int* in_sizes, int n_in,
                              void* d_out, int out_size, void* d_ws, size_t ws_size,
                              hipStream_t stream) {
  const float* base_feat = (const float*)d_in[0];
  const float* rois      = (const float*)d_in[1];
  const float* w_conv1   = (const float*)d_in[2];
  const float* w_cls     = (const float*)d_in[3];
  const float* w_bbox    = (const float*)d_in[4];
  float* out = (float*)d_out;
  char* ws = (char*)d_ws;

  unsigned short* featT = (unsigned short*)(ws + OFF_FEATT);
  unsigned short* w1b   = (unsigned short*)(ws + OFF_W1);
  unsigned short* Wc    = (unsigned short*)(ws + OFF_WC);
  int*            desc  = (int*)(ws + OFF_DESC);
  float*          X     = (float*)(ws + OFF_X);

  k_prep<<<8565, 256, 0, stream>>>(w_conv1, w_cls, w_bbox, rois, w1b, Wc, desc);
  k_tpose<<<dim3(64, 32, 4), 256, 0, stream>>>(base_feat, featT);
  k_gemm_conv1<<<dim3(32, 8, 4), 256, 0, stream>>>((const short*)featT, (const short*)w1b, X);

  if (ws_size >= ONEPASS_BYTES) {
    unsigned short* U = (unsigned short*)(ws + OFF_U1);
    unsigned short* P = (unsigned short*)(ws + OFF_P1);
    k_ubuild<<<1280, 256, 0, stream>>>(X, desc, U, 1280);
    k_poolgemm3<<<dim3(10, 49), 256, 0, stream>>>(U, Wc, P, 1280);
    k_finalize<<<640, 256, 0, stream>>>(P, out, 1280, 0);
  } else {
    unsigned short* U = (unsigned short*)(ws + OFF_U2);
    unsigned short* P = (unsigned short*)(ws + OFF_P2);
    for (int h = 0; h < 2; h++) {
      k_ubuild<<<640, 256, 0, stream>>>(X, desc + (size_t)h * 640 * 49 * 8, U, 640);
      k_poolgemm3<<<dim3(5, 49), 256, 0, stream>>>(U, Wc, P, 640);
      k_finalize<<<320, 256, 0, stream>>>(P, out, 640, h * 640);
    }
  }
}